// Round 6
// baseline (295.787 us; speedup 1.0000x reference)
//
#include <hip/hip_runtime.h>

typedef __bf16 bf16;
typedef __bf16 bf16x8 __attribute__((ext_vector_type(8)));
typedef float f32x4 __attribute__((ext_vector_type(4)));

#define T_ 4
#define B_ 8
#define C_ 512
#define D_ 768
#define H_ 8
#define HL_ 2
#define HD_ 96
#define MKV_ 192
#define M2_ 4096            // B*C
#define BCD_ 3145728        // B*C*D
#define M3_ 16384           // T*B*C
#define NCOMB 1152          // q(768) + k(192) + v(192)
#define SUSP_WIN 2e-4f

// async global->LDS, 16B per lane (dest = wave-uniform base + lane*16)
__device__ __forceinline__ void gld16(const bf16* g, bf16* l) {
    __builtin_amdgcn_global_load_lds(
        (const __attribute__((address_space(1))) unsigned int*)g,
        (__attribute__((address_space(3))) unsigned int*)l, 16, 0, 0);
}

// ---------------------------------------------------------------------------
// Kernel 1: fused prep — xs=lif(x) fp64 scan, weight hi/lo split, wo cvt,
// M_f32 zero. Grid-stride.
// ---------------------------------------------------------------------------
__global__ __launch_bounds__(256) void prep_kernel(
    const float* __restrict__ x, const float* __restrict__ q_w,
    const float* __restrict__ k_w, const float* __restrict__ v_w,
    const float* __restrict__ wo_w, bf16* __restrict__ xs,
    bf16* __restrict__ whi, bf16* __restrict__ wlo, bf16* __restrict__ wo_bf,
    float* __restrict__ M_f32)
{
    const int t0 = blockIdx.x * 256 + threadIdx.x;
    const int stride = gridDim.x * 256;
    for (int i = t0; i < BCD_; i += stride) {
        double v = 0.0;
        #pragma unroll
        for (int t = 0; t < T_; ++t) {
            v = v * 0.5 + (double)x[(size_t)t * BCD_ + i];
            float s = (v >= 1.0) ? 1.0f : 0.0f;
            xs[(size_t)t * BCD_ + i] = (bf16)s;
            if (s != 0.0f) v = 0.0;
        }
    }
    for (int i = t0; i < NCOMB * D_; i += stride) {
        int row = i / D_, col = i - row * D_;
        float v;
        if (row < 768)      v = q_w[(size_t)row * D_ + col];
        else if (row < 960) v = k_w[(size_t)(row - 768) * D_ + col];
        else                v = v_w[(size_t)(row - 960) * D_ + col];
        bf16 h = (bf16)v;
        whi[i] = h;
        wlo[i] = (bf16)(v - (float)h);
    }
    for (int i = t0; i < D_ * D_; i += stride)
        wo_bf[i] = (bf16)wo_w[i];
    for (int i = t0; i < 64 * HD_ * HD_; i += stride)
        M_f32[i] = 0.f;
}

// ---------------------------------------------------------------------------
// Kernel 2: combined spiking projection. Block 64(m)x128(n), BK=64, T fused
// in registers (acc[4][2][4]). XOR-swizzled LDS. LIF in epilogue; near-
// threshold trajectories fixed INLINE (wave-cooperative fp64, ballot-driven).
// ---------------------------------------------------------------------------
__global__ __launch_bounds__(256, 2) void proj_lif_kernel(
    const bf16* __restrict__ xs, const bf16* __restrict__ Whi,
    const bf16* __restrict__ Wlo,
    const float* __restrict__ q_w, const float* __restrict__ k_w,
    const float* __restrict__ v_w,
    bf16* __restrict__ q_sp, bf16* __restrict__ k_sp, bf16* __restrict__ v_sp)
{
    __shared__ __align__(16) bf16 Alds[T_][64 * 64];   // 32 KB
    __shared__ __align__(16) bf16 Hlds[128 * 64];      // 16 KB
    __shared__ __align__(16) bf16 Llds[128 * 64];      // 16 KB

    const int tid  = threadIdx.x;
    const int wave = tid >> 6, lane = tid & 63;
    const int m16  = lane & 15, quad = lane >> 4;
    const int wm   = wave >> 1, wn = wave & 1;
    const int m0   = blockIdx.x * 64;           // over M2
    const int n0   = blockIdx.y * 128;          // over NCOMB

    // wave's 64 output columns (never straddles q/k/v boundaries)
    const int colb = n0 + wn * 64;
    bf16* outp; int Nloc, cb;
    if (colb < 768)      { outp = q_sp; Nloc = 768; cb = colb; }
    else if (colb < 960) { outp = k_sp; Nloc = 192; cb = colb - 768; }
    else                 { outp = v_sp; Nloc = 192; cb = colb - 960; }

    f32x4 acc[T_][2][4];
    #pragma unroll
    for (int t = 0; t < T_; t++)
        #pragma unroll
        for (int a = 0; a < 2; a++)
            #pragma unroll
            for (int b = 0; b < 4; b++) { f32x4 z = {0.f,0.f,0.f,0.f}; acc[t][a][b] = z; }

    for (int k0 = 0; k0 < D_; k0 += 64) {
        __syncthreads();
        // A: 4t x 64row x 8slot = 2048 chunks; slot s holds seg s^((row>>1)&7)
        #pragma unroll
        for (int j = 0; j < 8; j++) {
            int ci = j * 256 + tid;
            int t = ci >> 9, rem = ci & 511, row = rem >> 3, slot = rem & 7;
            int seg = slot ^ ((row >> 1) & 7);
            gld16(xs + (size_t)(t * M2_ + m0 + row) * D_ + k0 + seg * 8, &Alds[t][rem * 8]);
        }
        // B hi/lo: 128row x 8slot = 1024 chunks each
        #pragma unroll
        for (int j = 0; j < 4; j++) {
            int ci = j * 256 + tid;
            int row = ci >> 3, slot = ci & 7;
            int seg = slot ^ ((row >> 1) & 7);
            gld16(Whi + (size_t)(n0 + row) * D_ + k0 + seg * 8, Hlds + ci * 8);
            gld16(Wlo + (size_t)(n0 + row) * D_ + k0 + seg * 8, Llds + ci * 8);
        }
        __syncthreads();

        #pragma unroll
        for (int kc = 0; kc < 2; kc++) {
            bf16x8 a[T_][2], bh[4], bl[4];
            #pragma unroll
            for (int mi = 0; mi < 2; mi++) {
                int row = wm * 32 + mi * 16 + m16;
                int off = row * 64 + (((kc * 4 + quad) ^ ((row >> 1) & 7)) * 8);
                #pragma unroll
                for (int t = 0; t < T_; t++)
                    a[t][mi] = *(const bf16x8*)&Alds[t][off];
            }
            #pragma unroll
            for (int ni = 0; ni < 4; ni++) {
                int row = wn * 64 + ni * 16 + m16;
                int off = row * 64 + (((kc * 4 + quad) ^ ((row >> 1) & 7)) * 8);
                bh[ni] = *(const bf16x8*)&Hlds[off];
                bl[ni] = *(const bf16x8*)&Llds[off];
            }
            #pragma unroll
            for (int ni = 0; ni < 4; ni++)
                #pragma unroll
                for (int t = 0; t < T_; t++)
                    #pragma unroll
                    for (int mi = 0; mi < 2; mi++) {
                        acc[t][mi][ni] = __builtin_amdgcn_mfma_f32_16x16x32_bf16(a[t][mi], bh[ni], acc[t][mi][ni], 0, 0, 0);
                        acc[t][mi][ni] = __builtin_amdgcn_mfma_f32_16x16x32_bf16(a[t][mi], bl[ni], acc[t][mi][ni], 0, 0, 0);
                    }
        }
    }

    // LIF scan (registers) + stores; suspects deferred to wave-coop fp64 fix
    unsigned suspectBits = 0;   // 32 slots: mi*16 + ni*4 + rr
    #pragma unroll
    for (int mi = 0; mi < 2; mi++)
        #pragma unroll
        for (int ni = 0; ni < 4; ni++)
            #pragma unroll
            for (int rr = 0; rr < 4; rr++) {
                int row = m0 + wm * 32 + mi * 16 + quad * 4 + rr;
                int lc  = cb + ni * 16 + m16;
                float v = 0.f;
                bool suspect = false;
                float spk[T_];
                #pragma unroll
                for (int t = 0; t < T_; t++) {
                    v = v * 0.5f + acc[t][mi][ni][rr];
                    float d = v - 1.0f;
                    if (fabsf(d) < SUSP_WIN) suspect = true;
                    float sp = (d >= 0.f) ? 1.f : 0.f;
                    v *= (1.f - sp);
                    spk[t] = sp;
                }
                if (!suspect) {
                    #pragma unroll
                    for (int t = 0; t < T_; t++)
                        outp[(size_t)(t * M2_ + row) * Nloc + lc] = (bf16)spk[t];
                } else {
                    suspectBits |= 1u << (mi * 16 + ni * 4 + rr);
                }
            }

    // wave-cooperative fp64 refinement of suspects (rare: ~0-3 per block)
    for (int slot = 0; slot < 32; ++slot) {
        unsigned long long mask = __ballot((suspectBits >> slot) & 1u);
        while (mask) {
            int l = __ffsll((long long)mask) - 1;
            mask &= mask - 1;
            int mi = slot >> 4, ni = (slot >> 2) & 3, rr = slot & 3;
            int row  = m0 + wm * 32 + mi * 16 + (l >> 4) * 4 + rr;
            int gcol = n0 + wn * 64 + ni * 16 + (l & 15);
            const float* W; bf16* op; int Nl, lc;
            if (gcol < 768)      { W = q_w + (size_t)gcol * D_;         op = q_sp; Nl = 768; lc = gcol; }
            else if (gcol < 960) { W = k_w + (size_t)(gcol - 768) * D_; op = k_sp; Nl = 192; lc = gcol - 768; }
            else                 { W = v_w + (size_t)(gcol - 960) * D_; op = v_sp; Nl = 192; lc = gcol - 960; }
            double v = 0.0;
            for (int t = 0; t < T_; ++t) {
                const bf16* ar = xs + (size_t)(t * M2_ + row) * D_;
                double y = 0.0;
                for (int k = lane; k < D_; k += 64)
                    y += (double)(float)ar[k] * (double)W[k];
                #pragma unroll
                for (int off = 1; off < 64; off <<= 1)
                    y += __shfl_xor(y, off);
                v = v * 0.5 + y;
                unsigned sp = (v >= 1.0) ? 1u : 0u;
                if (lane == 0) op[(size_t)(t * M2_ + row) * Nl + lc] = (bf16)(float)sp;
                if (sp) v = 0.0;
            }
        }
    }
}

// ---------------------------------------------------------------------------
// Kernel 3: partial k^T v, atomicAdd exact-integer fp32 into M_f32[g][j][d].
// Coalesced bf16x8 global loads + swizzled scalar LDS transpose writes.
// ---------------------------------------------------------------------------
__global__ __launch_bounds__(256) void ktv_kernel(
    const bf16* __restrict__ k_sp, const bf16* __restrict__ v_sp,
    float* __restrict__ M_f32)
{
    const int g    = blockIdx.x;
    const int cc   = blockIdx.y;
    const int kvh  = g % HL_;
    const int tb   = g / HL_;
    const int wave = threadIdx.x >> 6;
    const int lane = threadIdx.x & 63;
    const int m16  = lane & 15, quad = lane >> 4;

    __shared__ __align__(16) bf16 klds[96 * 40];
    __shared__ __align__(16) bf16 vlds[96 * 40];

    f32x4 acc[9];
    #pragma unroll
    for (int i = 0; i < 9; i++) { f32x4 z = {0.f,0.f,0.f,0.f}; acc[i] = z; }

    const bf16* kbase = k_sp + ((size_t)tb * C_ + cc * 128) * MKV_ + kvh * HD_;
    const bf16* vbase = v_sp + ((size_t)tb * C_ + cc * 128) * MKV_ + kvh * HD_;

    for (int c0 = 0; c0 < 128; c0 += 32) {
        __syncthreads();
        #pragma unroll
        for (int jj = 0; jj < 2; jj++) {
            int ci = jj * 256 + threadIdx.x;
            if (ci < 384) {
                int c = ci / 12, seg = ci - (ci / 12) * 12;
                bf16x8 kv = *(const bf16x8*)(kbase + (size_t)(c0 + c) * MKV_ + seg * 8);
                bf16x8 vv = *(const bf16x8*)(vbase + (size_t)(c0 + c) * MKV_ + seg * 8);
                int cs = c ^ ((seg & 3) << 3);
                #pragma unroll
                for (int j = 0; j < 8; j++) {
                    int d = seg * 8 + j;
                    klds[d * 40 + cs] = kv[j];
                    vlds[d * 40 + cs] = vv[j];
                }
            }
        }
        __syncthreads();
        #pragma unroll
        for (int i = 0; i < 9; i++) {
            int tile = wave + i * 4;
            int mt = tile / 6, nt = tile % 6;
            int rowA = mt * 16 + m16, rowB = nt * 16 + m16;
            bf16x8 a = *(const bf16x8*)&klds[rowA * 40 + ((quad * 8) ^ (((rowA >> 3) & 3) << 3))];
            bf16x8 b = *(const bf16x8*)&vlds[rowB * 40 + ((quad * 8) ^ (((rowB >> 3) & 3) << 3))];
            acc[i] = __builtin_amdgcn_mfma_f32_16x16x32_bf16(a, b, acc[i], 0, 0, 0);
        }
    }
    float* op = M_f32 + (size_t)g * HD_ * HD_;
    #pragma unroll
    for (int i = 0; i < 9; i++) {
        int tile = wave + i * 4;
        int mt = tile / 6, nt = tile % 6;
        #pragma unroll
        for (int r = 0; r < 4; r++) {
            int d = mt * 16 + quad * 4 + r;
            int j = nt * 16 + m16;
            atomicAdd(&op[(size_t)j * HD_ + d], acc[i][r]);
        }
    }
}

// ---------------------------------------------------------------------------
// Kernel 4: out_attn = 0.1 * q @ M. M staged from fp32 with on-the-fly hi/lo
// split into padded LDS (stride 104 -> conflict-free b128 reads).
// ---------------------------------------------------------------------------
__global__ __launch_bounds__(256) void qm_kernel(
    const bf16* __restrict__ q_sp, const float* __restrict__ M_f32,
    bf16* __restrict__ out_attn)
{
    const int tbh  = blockIdx.x;
    const int h    = tbh % H_;
    const int tb   = tbh / H_;
    const int g    = tb * HL_ + (h >> 2);
    const int wave = threadIdx.x >> 6;
    const int lane = threadIdx.x & 63;
    const int m16  = lane & 15, quad = lane >> 4;
    const int cw   = blockIdx.y * 128 + wave * 32;

    __shared__ __align__(16) bf16 Mh[96 * 104];
    __shared__ __align__(16) bf16 Ml[96 * 104];
    {
        const float* Mg = M_f32 + (size_t)g * HD_ * HD_;
        #pragma unroll
        for (int j = 0; j < 9; j++) {
            int ci = j * 256 + threadIdx.x;
            if (ci < 2304) {
                f32x4 m4 = *(const f32x4*)(Mg + ci * 4);
                int e = ci * 4, row = e / 96, colj = e - row * 96;
                #pragma unroll
                for (int xx = 0; xx < 4; xx++) {
                    float m = m4[xx];
                    bf16 hh = (bf16)m;
                    Mh[row * 104 + colj + xx] = hh;
                    Ml[row * 104 + colj + xx] = (bf16)(m - (float)hh);
                }
            }
        }
    }
    __syncthreads();

    f32x4 acc[2][6];
    #pragma unroll
    for (int mi = 0; mi < 2; mi++)
        #pragma unroll
        for (int nt = 0; nt < 6; nt++) { f32x4 z = {0.f,0.f,0.f,0.f}; acc[mi][nt] = z; }

    #pragma unroll
    for (int ks = 0; ks < 3; ++ks) {
        bf16x8 a[2];
        #pragma unroll
        for (int mi = 0; mi < 2; mi++)
            a[mi] = *(const bf16x8*)(q_sp + ((size_t)(tb * C_ + cw + mi * 16 + m16)) * D_
                                     + h * HD_ + ks * 32 + quad * 8);
        #pragma unroll
        for (int nt = 0; nt < 6; ++nt) {
            bf16x8 bh = *(const bf16x8*)&Mh[(nt * 16 + m16) * 104 + ks * 32 + quad * 8];
            bf16x8 bl = *(const bf16x8*)&Ml[(nt * 16 + m16) * 104 + ks * 32 + quad * 8];
            #pragma unroll
            for (int mi = 0; mi < 2; mi++) {
                acc[mi][nt] = __builtin_amdgcn_mfma_f32_16x16x32_bf16(a[mi], bh, acc[mi][nt], 0, 0, 0);
                acc[mi][nt] = __builtin_amdgcn_mfma_f32_16x16x32_bf16(a[mi], bl, acc[mi][nt], 0, 0, 0);
            }
        }
    }
    #pragma unroll
    for (int mi = 0; mi < 2; mi++)
        #pragma unroll
        for (int nt = 0; nt < 6; nt++)
            #pragma unroll
            for (int r = 0; r < 4; r++) {
                int c = cw + mi * 16 + quad * 4 + r;
                int j = nt * 16 + m16;
                out_attn[((size_t)(tb * C_ + c)) * D_ + h * HD_ + j] = (bf16)(0.1f * acc[mi][nt][r]);
            }
}

// ---------------------------------------------------------------------------
// Kernel 5: final = out_attn @ wo^T. 128x128 tile, BK=64, XOR-swizzled LDS.
// ---------------------------------------------------------------------------
__global__ __launch_bounds__(256) void final_gemm_kernel(
    const bf16* __restrict__ A, const bf16* __restrict__ W, float* __restrict__ out)
{
    __shared__ __align__(16) bf16 Alds[128 * 64];
    __shared__ __align__(16) bf16 Blds[128 * 64];
    const int tid  = threadIdx.x;
    const int wave = tid >> 6, lane = tid & 63;
    const int m16  = lane & 15, quad = lane >> 4;
    const int wm   = wave >> 1, wn = wave & 1;
    const int m0   = blockIdx.x * 128, n0 = blockIdx.y * 128;

    f32x4 acc[4][4];
    #pragma unroll
    for (int a = 0; a < 4; a++)
        #pragma unroll
        for (int b = 0; b < 4; b++) { f32x4 z = {0.f,0.f,0.f,0.f}; acc[a][b] = z; }

    for (int k0 = 0; k0 < D_; k0 += 64) {
        __syncthreads();
        #pragma unroll
        for (int j = 0; j < 4; j++) {
            int ci = j * 256 + tid;
            int row = ci >> 3, slot = ci & 7;
            int seg = slot ^ ((row >> 1) & 7);
            gld16(A + (size_t)(m0 + row) * D_ + k0 + seg * 8, Alds + ci * 8);
            gld16(W + (size_t)(n0 + row) * D_ + k0 + seg * 8, Blds + ci * 8);
        }
        __syncthreads();
        #pragma unroll
        for (int kc = 0; kc < 2; kc++) {
            bf16x8 a[4], b[4];
            #pragma unroll
            for (int mi = 0; mi < 4; mi++) {
                int row = wm * 64 + mi * 16 + m16;
                a[mi] = *(const bf16x8*)&Alds[row * 64 + (((kc * 4 + quad) ^ ((row >> 1) & 7)) * 8)];
            }
            #pragma unroll
            for (int ni = 0; ni < 4; ni++) {
                int row = wn * 64 + ni * 16 + m16;
                b[ni] = *(const bf16x8*)&Blds[row * 64 + (((kc * 4 + quad) ^ ((row >> 1) & 7)) * 8)];
            }
            #pragma unroll
            for (int mi = 0; mi < 4; mi++)
                #pragma unroll
                for (int ni = 0; ni < 4; ni++)
                    acc[mi][ni] = __builtin_amdgcn_mfma_f32_16x16x32_bf16(a[mi], b[ni], acc[mi][ni], 0, 0, 0);
        }
    }
    #pragma unroll
    for (int mi = 0; mi < 4; mi++)
        #pragma unroll
        for (int ni = 0; ni < 4; ni++)
            #pragma unroll
            for (int r = 0; r < 4; r++) {
                int row = m0 + wm * 64 + mi * 16 + quad * 4 + r;
                int col = n0 + wn * 64 + ni * 16 + m16;
                out[(size_t)row * D_ + col] = acc[mi][ni][r];
            }
}

// ---------------------------------------------------------------------------
extern "C" void kernel_launch(void* const* d_in, const int* in_sizes, int n_in,
                              void* d_out, int out_size, void* d_ws, size_t ws_size,
                              hipStream_t stream) {
    const float* x    = (const float*)d_in[0];
    const float* q_w  = (const float*)d_in[1];
    const float* k_w  = (const float*)d_in[2];
    const float* v_w  = (const float*)d_in[3];
    const float* wo_w = (const float*)d_in[4];
    float* out = (float*)d_out;

    char* ws = (char*)d_ws;
    bf16* xs    = (bf16*)(ws);                  // 25,165,824  (T,M2,768)
    bf16* q_sp  = (bf16*)(ws + 25165824);       // 25,165,824  (T,M2,768)
    bf16* k_sp  = (bf16*)(ws + 50331648);       //  6,291,456  (T,M2,192)
    bf16* v_sp  = (bf16*)(ws + 56623104);       //  6,291,456  (T,M2,192)
    bf16* whi   = (bf16*)(ws + 62914560);       //  1,769,472  (1152,768)
    bf16* wlo   = (bf16*)(ws + 64684032);       //  1,769,472
    bf16* wo_bf = (bf16*)(ws + 66453504);       //  1,179,648
    float* M_f32 = (float*)(ws + 67633152);     //  2,359,296  (64,96,96)
    bf16* out_attn = xs;                        // alias: xs dead after proj

    hipLaunchKernelGGL(prep_kernel, dim3(2048), dim3(256), 0, stream,
                       x, q_w, k_w, v_w, wo_w, xs, whi, wlo, wo_bf, M_f32);
    hipLaunchKernelGGL(proj_lif_kernel, dim3(M2_ / 64, NCOMB / 128), dim3(256), 0, stream,
                       xs, whi, wlo, q_w, k_w, v_w, q_sp, k_sp, v_sp);
    hipLaunchKernelGGL(ktv_kernel, dim3(T_ * B_ * HL_, 4), dim3(256), 0, stream,
                       k_sp, v_sp, M_f32);
    hipLaunchKernelGGL(qm_kernel, dim3(T_ * B_ * H_, C_ / 128), dim3(256), 0, stream,
                       q_sp, M_f32, out_attn);
    hipLaunchKernelGGL(final_gemm_kernel, dim3(M3_ / 128, D_ / 128), dim3(256), 0, stream,
                       out_attn, wo_bf, out);
}